// Round 1
// 523.193 us; speedup vs baseline: 1.0563x; 1.0563x over previous
//
#include <hip/hip_runtime.h>
#include <hip/hip_bf16.h>
#include <stdint.h>

// Problem constants: B=8, T=256, S=400, H=512, VOCAB=32000
#define BB 8
#define TT 256
#define SS 400
#define HH 512
#define VV 32000
#define MM (BB*TT)      // 2048 rows
#define KK 512
#define NBLK (VV/128)   // 250 n-blocks in gemm2
#define MBLK (MM/128)   // 16 m-blocks
#define G2BLOCKS (NBLK*MBLK)  // 4000, divisible by 8 XCDs

typedef __bf16 bf16x8 __attribute__((ext_vector_type(8)));
typedef float  f32x4  __attribute__((ext_vector_type(4)));
typedef unsigned short ushort8 __attribute__((ext_vector_type(8)));

__device__ __forceinline__ unsigned short f2bf(float x) {
    union { float f; unsigned u; } v; v.f = x;
    unsigned r = v.u + 0x7fffu + ((v.u >> 16) & 1u);   // RNE
    return (unsigned short)(r >> 16);
}
__device__ __forceinline__ float bf2f(unsigned short u) {
    union { unsigned u; float f; } v; v.u = ((unsigned)u) << 16; return v.f;
}

__device__ __forceinline__ void async_ld16(const void* g, void* lds) {
    __builtin_amdgcn_global_load_lds(
        (const __attribute__((address_space(1))) unsigned int*)g,
        (__attribute__((address_space(3))) unsigned int*)lds,
        16, 0, 0);
}

// ---------------- elementwise fp32 -> bf16 ----------------
__global__ __launch_bounds__(256) void f32_to_bf16_kernel(const float* __restrict__ x,
                                                          unsigned short* __restrict__ y, int n4) {
    int i = blockIdx.x * blockDim.x + threadIdx.x;
    if (i < n4) {
        float4 v = ((const float4*)x)[i];
        ushort4 o;
        o.x = f2bf(v.x); o.y = f2bf(v.y); o.z = f2bf(v.z); o.w = f2bf(v.w);
        ((ushort4*)y)[i] = o;
    }
}

// ---------------- transpose (K x N fp32) -> (N x K bf16) ----------------
__global__ __launch_bounds__(256) void transpose_bf16_kernel(const float* __restrict__ W,
                                                             unsigned short* __restrict__ Wt,
                                                             int K, int N) {
    __shared__ float tile[32][33];
    int n0 = blockIdx.x * 32, k0 = blockIdx.y * 32;
    int t = threadIdx.x;
    int r  = t >> 3;          // 0..31
    int c4 = (t & 7) * 4;     // 0,4,...,28
    float4 v = *(const float4*)(W + (size_t)(k0 + r) * N + n0 + c4);
    tile[r][c4 + 0] = v.x; tile[r][c4 + 1] = v.y;
    tile[r][c4 + 2] = v.z; tile[r][c4 + 3] = v.w;
    __syncthreads();
    ushort4 o;
    o.x = f2bf(tile[c4 + 0][r]);
    o.y = f2bf(tile[c4 + 1][r]);
    o.z = f2bf(tile[c4 + 2][r]);
    o.w = f2bf(tile[c4 + 3][r]);
    *(ushort4*)(Wt + (size_t)(n0 + r) * K + k0 + c4) = o;
}

// ---------------- p_gen ----------------
__global__ __launch_bounds__(256) void pgen_kernel(const float* __restrict__ state,
                                                   const float* __restrict__ wp,
                                                   const float* __restrict__ bp,
                                                   float* __restrict__ pg) {
    int row  = blockIdx.x * 4 + (threadIdx.x >> 6);
    int lane = threadIdx.x & 63;
    const float* s = state + (size_t)row * (2 * HH);
    float acc = 0.f;
    for (int j = lane; j < 2 * HH; j += 64) acc += s[j] * wp[j];
    for (int off = 32; off; off >>= 1) acc += __shfl_xor(acc, off, 64);
    if (lane == 0) pg[row] = 1.f / (1.f + __expf(-(acc + bp[0])));
}

// ---------------- GEMM1: hidden = bf16(A @ W1t^T + b1) ----------------
__global__ __launch_bounds__(256) void gemm1_kernel(const unsigned short* __restrict__ A,
                                                    const unsigned short* __restrict__ Bt,
                                                    const float* __restrict__ bias,
                                                    unsigned short* __restrict__ out, int N) {
    __shared__ __align__(16) unsigned short As[128 * 32];
    __shared__ __align__(16) unsigned short Bs[128 * 32];
    const int tid = threadIdx.x, wave = tid >> 6, lane = tid & 63;
    const int m0 = blockIdx.y * 128, n0 = blockIdx.x * 128;
    const int q = lane >> 4, r_ = lane & 15;
    const int wm = (wave >> 1) * 64, wn = (wave & 1) * 64;
    f32x4 acc[4][4] = {};
    for (int k0 = 0; k0 < KK; k0 += 32) {
        #pragma unroll
        for (int rr = 0; rr < 2; ++rr) {
            int cc = tid + rr * 256, row = cc >> 2, col = (cc & 3) * 8;
            async_ld16(A  + (size_t)(m0 + row) * KK + k0 + col, (char*)As + (size_t)cc * 16);
            async_ld16(Bt + (size_t)(n0 + row) * KK + k0 + col, (char*)Bs + (size_t)cc * 16);
        }
        __syncthreads();
        bf16x8 a[4], b[4];
        #pragma unroll
        for (int i = 0; i < 4; ++i) {
            a[i] = *(const bf16x8*)(As + (wm + i * 16 + r_) * 32 + q * 8);
            b[i] = *(const bf16x8*)(Bs + (wn + i * 16 + r_) * 32 + q * 8);
        }
        #pragma unroll
        for (int mi = 0; mi < 4; ++mi)
            #pragma unroll
            for (int ni = 0; ni < 4; ++ni)
                acc[mi][ni] = __builtin_amdgcn_mfma_f32_16x16x32_bf16(a[mi], b[ni], acc[mi][ni], 0, 0, 0);
        __syncthreads();
    }
    #pragma unroll
    for (int mi = 0; mi < 4; ++mi)
        #pragma unroll
        for (int ni = 0; ni < 4; ++ni) {
            int n = n0 + wn + ni * 16 + r_;
            float bv = bias[n];
            #pragma unroll
            for (int rg = 0; rg < 4; ++rg) {
                int m = m0 + wm + mi * 16 + q * 4 + rg;
                out[(size_t)m * N + n] = f2bf(acc[mi][ni][rg] + bv);
            }
        }
}

// ---------------- GEMM2 + exp epilogue + per-block row sums ----------------
// E[m][n] = exp(hidden@w2t^T + b2); Zpart[nblk][m] = sum over this block's 128 cols.
//
// XCD-aware remap (bijective, 4000 % 8 == 0): dispatch round-robins blockIdx
// across the 8 XCDs; give each XCD a contiguous chunk of 500 logical ids,
// ordered m-inner so all 16 m-blocks of one B-panel (131 KB w2t) run
// back-to-back on ONE XCD. Per-XCD L2 working set = all of A (2 MB) +
// a few B panels < 4 MiB, so w2t is fetched from HBM ~once instead of ~16x.
template <bool E_BF16>
__global__ __launch_bounds__(256) void gemm2_exp_kernel(const unsigned short* __restrict__ A,
                                                        const unsigned short* __restrict__ Bt,
                                                        const float* __restrict__ bias,
                                                        void* __restrict__ E,
                                                        float* __restrict__ Zpart) {
    __shared__ __align__(16) unsigned short As[128 * 32];
    __shared__ __align__(16) unsigned short Bs[128 * 32];
    __shared__ float rowsum[128];
    const int tid = threadIdx.x, wave = tid >> 6, lane = tid & 63;

    // --- block remap: bid -> (n-panel nb, m-block mb) ---
    const int bid = blockIdx.x;                 // 0..3999
    const int xcd = bid & 7;                    // empirical: XCD = bid % 8
    const int sub = bid >> 3;                   // 0..499
    const int lin = xcd * (G2BLOCKS / 8) + sub; // contiguous chunk per XCD
    const int nb  = lin >> 4;                   // 0..249 (panel, shared by 16 m-blocks)
    const int mb  = lin & 15;                   // 0..15  (m inner)
    const int m0 = mb * 128, n0 = nb * 128;

    const int q = lane >> 4, r_ = lane & 15;
    const int wm = (wave >> 1) * 64, wn = (wave & 1) * 64;
    f32x4 acc[4][4] = {};
    for (int k0 = 0; k0 < KK; k0 += 32) {
        #pragma unroll
        for (int rr = 0; rr < 2; ++rr) {
            int cc = tid + rr * 256, row = cc >> 2, col = (cc & 3) * 8;
            async_ld16(A  + (size_t)(m0 + row) * KK + k0 + col, (char*)As + (size_t)cc * 16);
            async_ld16(Bt + (size_t)(n0 + row) * KK + k0 + col, (char*)Bs + (size_t)cc * 16);
        }
        __syncthreads();
        bf16x8 a[4], b[4];
        #pragma unroll
        for (int i = 0; i < 4; ++i) {
            a[i] = *(const bf16x8*)(As + (wm + i * 16 + r_) * 32 + q * 8);
            b[i] = *(const bf16x8*)(Bs + (wn + i * 16 + r_) * 32 + q * 8);
        }
        #pragma unroll
        for (int mi = 0; mi < 4; ++mi)
            #pragma unroll
            for (int ni = 0; ni < 4; ++ni)
                acc[mi][ni] = __builtin_amdgcn_mfma_f32_16x16x32_bf16(a[mi], b[ni], acc[mi][ni], 0, 0, 0);
        __syncthreads();
    }

    if (tid < 128) rowsum[tid] = 0.f;
    __syncthreads();

    float rowpart[16];   // [mi*4+rg] = sum over this thread's 4 cols
    #pragma unroll
    for (int i = 0; i < 16; ++i) rowpart[i] = 0.f;

    #pragma unroll
    for (int mi = 0; mi < 4; ++mi)
        #pragma unroll
        for (int ni = 0; ni < 4; ++ni) {
            int n = n0 + wn + ni * 16 + r_;
            float bv = bias[n];
            #pragma unroll
            for (int rg = 0; rg < 4; ++rg) {
                int m = m0 + wm + mi * 16 + q * 4 + rg;
                float e = __expf(acc[mi][ni][rg] + bv);
                if (E_BF16)
                    ((unsigned short*)E)[(size_t)m * VV + n] = f2bf(e);
                else
                    ((float*)E)[(size_t)m * VV + n] = e;
                rowpart[mi * 4 + rg] += e;
            }
        }
    // reduce across the 16 lanes of each quad-row group
    #pragma unroll
    for (int i = 0; i < 16; ++i) {
        float v = rowpart[i];
        v += __shfl_xor(v, 1, 64);
        v += __shfl_xor(v, 2, 64);
        v += __shfl_xor(v, 4, 64);
        v += __shfl_xor(v, 8, 64);
        rowpart[i] = v;
    }
    if (r_ == 0) {
        #pragma unroll
        for (int mi = 0; mi < 4; ++mi)
            #pragma unroll
            for (int rg = 0; rg < 4; ++rg)
                atomicAdd(&rowsum[wm + mi * 16 + q * 4 + rg], rowpart[mi * 4 + rg]);
    }
    __syncthreads();
    if (tid < 128) Zpart[(size_t)nb * MM + m0 + tid] = rowsum[tid];
}

// ---------------- Z[row] = sum over nblk of Zpart ----------------
__global__ __launch_bounds__(256) void zfinal_kernel(const float* __restrict__ Zpart,
                                                     float* __restrict__ Z) {
    int row = blockIdx.x * 256 + threadIdx.x;
    float s = 0.f;
    for (int nb = 0; nb < NBLK; ++nb) s += Zpart[(size_t)nb * MM + row];
    Z[row] = s;
}

// ---------------- finalize: out = log(pg/Z * E + scatter((1-pg)*attn) + 1e-12) ----------------
// 8 parts per row, CH=4000 columns per block, dense LDS accumulator.
template <bool E_BF16>
__global__ __launch_bounds__(256) void finalize_kernel(const void* __restrict__ E,
                                                       float* __restrict__ out,
                                                       const float* __restrict__ pg_arr,
                                                       const float* __restrict__ Z,
                                                       const float* __restrict__ attn,
                                                       const int* __restrict__ enc) {
    constexpr int CH = VV / 8;  // 4000
    __shared__ float acc[CH];
    int bid = blockIdx.x;
    int row = bid >> 3;
    int part = bid & 7;
    int nbase = part * CH;
    f32x4* acc4 = (f32x4*)acc;
    for (int j = threadIdx.x; j < CH / 4; j += 256) acc4[j] = (f32x4){0.f, 0.f, 0.f, 0.f};
    float pg = pg_arr[row];
    float scale = pg / Z[row];
    float om = 1.f - pg;
    int batch = row / TT;
    __syncthreads();
    for (int s = threadIdx.x; s < SS; s += 256) {
        int idx = enc[batch * SS + s];
        if (idx >= nbase && idx < nbase + CH)
            atomicAdd(&acc[idx - nbase], om * attn[(size_t)row * SS + s]);
    }
    __syncthreads();
    size_t base = (size_t)row * VV + nbase;
    for (int j = threadIdx.x * 8; j < CH; j += 2048) {
        float e[8];
        if (E_BF16) {
            ushort8 u = *(const ushort8*)((const unsigned short*)E + base + j);
            #pragma unroll
            for (int i = 0; i < 8; ++i) e[i] = bf2f(u[i]);
        } else {
            f32x4 u0 = *(const f32x4*)((const float*)E + base + j);
            f32x4 u1 = *(const f32x4*)((const float*)E + base + j + 4);
            e[0]=u0[0]; e[1]=u0[1]; e[2]=u0[2]; e[3]=u0[3];
            e[4]=u1[0]; e[5]=u1[1]; e[6]=u1[2]; e[7]=u1[3];
        }
        // vectorized LDS reads (j is a multiple of 8 -> f32x4-aligned)
        f32x4 a0 = acc4[(j >> 2) + 0];
        f32x4 a1 = acc4[(j >> 2) + 1];
        f32x4 o0, o1;
        #pragma unroll
        for (int i = 0; i < 4; ++i) o0[i] = __logf(scale * e[i]     + a0[i] + 1e-12f);
        #pragma unroll
        for (int i = 0; i < 4; ++i) o1[i] = __logf(scale * e[4 + i] + a1[i] + 1e-12f);
        *(f32x4*)(out + base + j)     = o0;
        *(f32x4*)(out + base + j + 4) = o1;
    }
}

extern "C" void kernel_launch(void* const* d_in, const int* in_sizes, int n_in,
                              void* d_out, int out_size, void* d_ws, size_t ws_size,
                              hipStream_t stream) {
    const float* s_output = (const float*)d_in[0];
    const float* state_in = (const float*)d_in[1];
    const float* attn     = (const float*)d_in[2];
    const int*   enc      = (const int*)  d_in[3];
    const float* w_pgen   = (const float*)d_in[4];
    const float* b_pgen   = (const float*)d_in[5];
    const float* w1       = (const float*)d_in[6];
    const float* b1       = (const float*)d_in[7];
    const float* w2       = (const float*)d_in[8];
    const float* b2       = (const float*)d_in[9];

    // workspace layout (bytes). Zpart aliases sA (sA dead after gemm1).
    char* ws = (char*)d_ws;
    float*          pg     = (float*)(ws + 0);                 // 2048 f32
    float*          Z      = (float*)(ws + 8192);              // 2048 f32
    unsigned short* hidden = (unsigned short*)(ws + 16384);    // 2048x512 bf16
    unsigned short* sA     = (unsigned short*)(ws + 2113536);  // 2048x512 bf16
    float*          Zpart  = (float*)(ws + 2113536);           // 250x2048 f32 (aliases sA)
    unsigned short* w1t    = (unsigned short*)(ws + 4210688);  // 512x512 bf16
    unsigned short* w2t    = (unsigned short*)(ws + 4734976);  // 32000x512 bf16 (end 37,502,976)
    unsigned short* Ebf    = (unsigned short*)(ws + 37502976); // 2048x32000 bf16 (needs big ws)

    const size_t NEED_BIG = 37502976ull + 2ull * MM * VV;      // 168,574,976
    const bool big = (ws_size >= NEED_BIG);

    f32_to_bf16_kernel<<<(MM * HH / 4 + 255) / 256, 256, 0, stream>>>(s_output, sA, MM * HH / 4);
    transpose_bf16_kernel<<<dim3(HH / 32, KK / 32), 256, 0, stream>>>(w1, w1t, KK, HH);
    transpose_bf16_kernel<<<dim3(VV / 32, KK / 32), 256, 0, stream>>>(w2, w2t, KK, VV);
    pgen_kernel<<<MM / 4, 256, 0, stream>>>(state_in, w_pgen, b_pgen, pg);
    gemm1_kernel<<<dim3(HH / 128, MM / 128), 256, 0, stream>>>(sA, w1t, b1, hidden, HH);

    if (big) {
        gemm2_exp_kernel<true><<<G2BLOCKS, 256, 0, stream>>>(hidden, w2t, b2, Ebf, Zpart);
        zfinal_kernel<<<MM / 256, 256, 0, stream>>>(Zpart, Z);
        finalize_kernel<true><<<MM * 8, 256, 0, stream>>>(Ebf, (float*)d_out, pg, Z, attn, enc);
    } else {
        gemm2_exp_kernel<false><<<G2BLOCKS, 256, 0, stream>>>(hidden, w2t, b2, d_out, Zpart);
        zfinal_kernel<<<MM / 256, 256, 0, stream>>>(Zpart, Z);
        finalize_kernel<false><<<MM * 8, 256, 0, stream>>>(d_out, (float*)d_out, pg, Z, attn, enc);
    }
}

// Round 2
// 511.532 us; speedup vs baseline: 1.0804x; 1.0228x over previous
//
#include <hip/hip_runtime.h>
#include <hip/hip_bf16.h>
#include <stdint.h>

// Problem constants: B=8, T=256, S=400, H=512, VOCAB=32000
#define BB 8
#define TT 256
#define SS 400
#define HH 512
#define VV 32000
#define MM (BB*TT)      // 2048 rows
#define KK 512

// gemm2 (8-phase) geometry
#define BM2 256
#define BN2 256
#define BK2 64
#define NBLK2 (VV/BN2)        // 125 n-blocks
#define MBLK2 (MM/BM2)        // 8 m-blocks
#define G2B (NBLK2*MBLK2)     // 1000 blocks (divisible by 8 XCDs)

typedef __bf16 bf16x8 __attribute__((ext_vector_type(8)));
typedef float  f32x4  __attribute__((ext_vector_type(4)));
typedef unsigned short ushort8 __attribute__((ext_vector_type(8)));

__device__ __forceinline__ unsigned short f2bf(float x) {
    union { float f; unsigned u; } v; v.f = x;
    unsigned r = v.u + 0x7fffu + ((v.u >> 16) & 1u);   // RNE
    return (unsigned short)(r >> 16);
}
__device__ __forceinline__ float bf2f(unsigned short u) {
    union { unsigned u; float f; } v; v.u = ((unsigned)u) << 16; return v.f;
}

__device__ __forceinline__ void async_ld16(const void* g, void* lds) {
    __builtin_amdgcn_global_load_lds(
        (const __attribute__((address_space(1))) unsigned int*)g,
        (__attribute__((address_space(3))) unsigned int*)lds,
        16, 0, 0);
}

// ---------------- elementwise fp32 -> bf16 ----------------
__global__ __launch_bounds__(256) void f32_to_bf16_kernel(const float* __restrict__ x,
                                                          unsigned short* __restrict__ y, int n4) {
    int i = blockIdx.x * blockDim.x + threadIdx.x;
    if (i < n4) {
        float4 v = ((const float4*)x)[i];
        ushort4 o;
        o.x = f2bf(v.x); o.y = f2bf(v.y); o.z = f2bf(v.z); o.w = f2bf(v.w);
        ((ushort4*)y)[i] = o;
    }
}

// ---------------- transpose (K x N fp32) -> (N x K bf16) ----------------
__global__ __launch_bounds__(256) void transpose_bf16_kernel(const float* __restrict__ W,
                                                             unsigned short* __restrict__ Wt,
                                                             int K, int N) {
    __shared__ float tile[32][33];
    int n0 = blockIdx.x * 32, k0 = blockIdx.y * 32;
    int t = threadIdx.x;
    int r  = t >> 3;          // 0..31
    int c4 = (t & 7) * 4;     // 0,4,...,28
    float4 v = *(const float4*)(W + (size_t)(k0 + r) * N + n0 + c4);
    tile[r][c4 + 0] = v.x; tile[r][c4 + 1] = v.y;
    tile[r][c4 + 2] = v.z; tile[r][c4 + 3] = v.w;
    __syncthreads();
    ushort4 o;
    o.x = f2bf(tile[c4 + 0][r]);
    o.y = f2bf(tile[c4 + 1][r]);
    o.z = f2bf(tile[c4 + 2][r]);
    o.w = f2bf(tile[c4 + 3][r]);
    *(ushort4*)(Wt + (size_t)(n0 + r) * K + k0 + c4) = o;
}

// ---------------- p_gen ----------------
__global__ __launch_bounds__(256) void pgen_kernel(const float* __restrict__ state,
                                                   const float* __restrict__ wp,
                                                   const float* __restrict__ bp,
                                                   float* __restrict__ pg) {
    int row  = blockIdx.x * 4 + (threadIdx.x >> 6);
    int lane = threadIdx.x & 63;
    const float* s = state + (size_t)row * (2 * HH);
    float acc = 0.f;
    for (int j = lane; j < 2 * HH; j += 64) acc += s[j] * wp[j];
    for (int off = 32; off; off >>= 1) acc += __shfl_xor(acc, off, 64);
    if (lane == 0) pg[row] = 1.f / (1.f + __expf(-(acc + bp[0])));
}

// ---------------- GEMM1: hidden = bf16(A @ W1t^T + b1) ----------------
__global__ __launch_bounds__(256) void gemm1_kernel(const unsigned short* __restrict__ A,
                                                    const unsigned short* __restrict__ Bt,
                                                    const float* __restrict__ bias,
                                                    unsigned short* __restrict__ out, int N) {
    __shared__ __align__(16) unsigned short As[128 * 32];
    __shared__ __align__(16) unsigned short Bs[128 * 32];
    const int tid = threadIdx.x, wave = tid >> 6, lane = tid & 63;
    const int m0 = blockIdx.y * 128, n0 = blockIdx.x * 128;
    const int q = lane >> 4, r_ = lane & 15;
    const int wm = (wave >> 1) * 64, wn = (wave & 1) * 64;
    f32x4 acc[4][4] = {};
    for (int k0 = 0; k0 < KK; k0 += 32) {
        #pragma unroll
        for (int rr = 0; rr < 2; ++rr) {
            int cc = tid + rr * 256, row = cc >> 2, col = (cc & 3) * 8;
            async_ld16(A  + (size_t)(m0 + row) * KK + k0 + col, (char*)As + (size_t)cc * 16);
            async_ld16(Bt + (size_t)(n0 + row) * KK + k0 + col, (char*)Bs + (size_t)cc * 16);
        }
        __syncthreads();
        bf16x8 a[4], b[4];
        #pragma unroll
        for (int i = 0; i < 4; ++i) {
            a[i] = *(const bf16x8*)(As + (wm + i * 16 + r_) * 32 + q * 8);
            b[i] = *(const bf16x8*)(Bs + (wn + i * 16 + r_) * 32 + q * 8);
        }
        #pragma unroll
        for (int mi = 0; mi < 4; ++mi)
            #pragma unroll
            for (int ni = 0; ni < 4; ++ni)
                acc[mi][ni] = __builtin_amdgcn_mfma_f32_16x16x32_bf16(a[mi], b[ni], acc[mi][ni], 0, 0, 0);
        __syncthreads();
    }
    #pragma unroll
    for (int mi = 0; mi < 4; ++mi)
        #pragma unroll
        for (int ni = 0; ni < 4; ++ni) {
            int n = n0 + wn + ni * 16 + r_;
            float bv = bias[n];
            #pragma unroll
            for (int rg = 0; rg < 4; ++rg) {
                int m = m0 + wm + mi * 16 + q * 4 + rg;
                out[(size_t)m * N + n] = f2bf(acc[mi][ni][rg] + bv);
            }
        }
}

// ---------------- GEMM2 (256x256, BK=64, 8 waves, 4-phase interleave) ----------------
// E[m][n] = exp(hidden@w2t^T + b2); Zpart[nb][m] = sum over this block's 256 cols.
//
// LDS: 2 buffers x (A 32KB | B 32KB) = 128 KB, XOR-swizzled (byte ^= (row&7)<<4).
// Swizzle is both-sides: global_load_lds writes linearly from a pre-inverse-swizzled
// global source; ds_read applies the same XOR. Per K-tile: 4 quadrant phases, each
// {2x global_load_lds prefetch of t+1, 12x ds_read_b128, setprio(1), 16 MFMA,
// setprio(0), raw s_barrier}. vmcnt(0) only at tile boundary (prefetches stay in
// flight across the 4 phase barriers).
template <bool E_BF16>
__global__ __launch_bounds__(512, 2) void gemm2_exp_kernel(const unsigned short* __restrict__ A,
                                                           const unsigned short* __restrict__ Bt,
                                                           const float* __restrict__ bias,
                                                           void* __restrict__ E,
                                                           float* __restrict__ Zpart) {
    __shared__ __align__(16) char lds[2][65536];   // [buf][ A:32768 | B:32768 ]
    const int tid = threadIdx.x, wave = tid >> 6, lane = tid & 63;
    const int q = lane >> 4, r_ = lane & 15;
    const int wm = wave >> 2;     // 0..1  -> M offset wm*128
    const int wn = wave & 3;      // 0..3  -> N offset wn*64

    // XCD-aware remap (bijective: 1000 % 8 == 0), m-inner within each XCD chunk
    const int bid = blockIdx.x;
    const int xcd = bid & 7;
    const int sub = bid >> 3;                  // 0..124
    const int lin = xcd * (G2B / 8) + sub;     // contiguous chunk per XCD
    const int nb  = lin >> 3;                  // 0..124
    const int mb  = lin & 7;                   // 0..7
    const int m0 = mb * BM2, n0 = nb * BN2;

    f32x4 acc[8][4] = {};   // [mi][ni] 16x16 fragments; wave patch = 128x64

    // stage chunk j (0..3) of K-tile t for both A and B into buf[t&1]
    auto stage = [&](int t, int j) {
        int c   = tid + j * 512;               // 0..2047 chunk index (16B chunks)
        int row = c >> 3;                      // 0..255 tile row
        int colb = (c & 7) * 16;               // linear LDS col-byte 0..112
        int src  = colb ^ ((row & 7) << 4);    // inverse-swizzled source col-byte
        char* base = lds[t & 1];
        async_ld16((const char*)A  + ((size_t)(m0 + row) * KK + t * BK2) * 2 + src,
                   base + c * 16);
        async_ld16((const char*)Bt + ((size_t)(n0 + row) * KK + t * BK2) * 2 + src,
                   base + 32768 + c * 16);
    };

    // prologue: stage tile 0, drain, barrier
    #pragma unroll
    for (int j = 0; j < 4; ++j) stage(0, j);
    asm volatile("s_waitcnt vmcnt(0)" ::: "memory");
    __builtin_amdgcn_s_barrier();
    __builtin_amdgcn_sched_barrier(0);

    for (int t = 0; t < KK / BK2; ++t) {       // 8 K-tiles
        char* buf = lds[t & 1];
        #pragma unroll
        for (int p = 0; p < 4; ++p) {
            if (t < KK / BK2 - 1) stage(t + 1, p);
            const int mib = (p >> 1) * 4;      // quadrant: 4 mi x 2 ni
            const int nib = (p & 1) * 2;
            bf16x8 af[4][2], bg[2][2];
            #pragma unroll
            for (int mi = 0; mi < 4; ++mi)
                #pragma unroll
                for (int ks = 0; ks < 2; ++ks) {
                    int row = wm * 128 + (mib + mi) * 16 + r_;
                    int cb  = (ks * 64 + q * 16) ^ ((row & 7) << 4);
                    af[mi][ks] = *(const bf16x8*)(buf + row * 128 + cb);
                }
            #pragma unroll
            for (int ni = 0; ni < 2; ++ni)
                #pragma unroll
                for (int ks = 0; ks < 2; ++ks) {
                    int row = wn * 64 + (nib + ni) * 16 + r_;
                    int cb  = (ks * 64 + q * 16) ^ ((row & 7) << 4);
                    bg[ni][ks] = *(const bf16x8*)(buf + 32768 + row * 128 + cb);
                }
            __builtin_amdgcn_s_setprio(1);
            #pragma unroll
            for (int mi = 0; mi < 4; ++mi)
                #pragma unroll
                for (int ni = 0; ni < 2; ++ni)
                    #pragma unroll
                    for (int ks = 0; ks < 2; ++ks)
                        acc[mib + mi][nib + ni] = __builtin_amdgcn_mfma_f32_16x16x32_bf16(
                            af[mi][ks], bg[ni][ks], acc[mib + mi][nib + ni], 0, 0, 0);
            __builtin_amdgcn_s_setprio(0);
            __builtin_amdgcn_sched_barrier(0);
            __builtin_amdgcn_s_barrier();      // raw barrier: prefetches stay in flight
            __builtin_amdgcn_sched_barrier(0);
        }
        // tile boundary: next tile's data must have landed; all waves past reads of buf
        asm volatile("s_waitcnt vmcnt(0)" ::: "memory");
        __builtin_amdgcn_sched_barrier(0);
        __builtin_amdgcn_s_barrier();
        __builtin_amdgcn_sched_barrier(0);
    }

    // ---- epilogue: exp, E store, per-row sums (rowsum overlays dead staging LDS) ----
    float* rowsum = (float*)&lds[0][0];
    if (tid < BM2) rowsum[tid] = 0.f;
    __syncthreads();

    float bv[4];
    #pragma unroll
    for (int ni = 0; ni < 4; ++ni) bv[ni] = bias[n0 + wn * 64 + ni * 16 + r_];

    #pragma unroll
    for (int mi = 0; mi < 8; ++mi) {
        float rp[4] = {0.f, 0.f, 0.f, 0.f};
        #pragma unroll
        for (int ni = 0; ni < 4; ++ni) {
            int n = n0 + wn * 64 + ni * 16 + r_;
            #pragma unroll
            for (int rg = 0; rg < 4; ++rg) {
                int m = m0 + wm * 128 + mi * 16 + q * 4 + rg;
                float e = __expf(acc[mi][ni][rg] + bv[ni]);
                if (E_BF16)
                    ((unsigned short*)E)[(size_t)m * VV + n] = f2bf(e);
                else
                    ((float*)E)[(size_t)m * VV + n] = e;
                rp[rg] += e;
            }
        }
        #pragma unroll
        for (int rg = 0; rg < 4; ++rg) {
            float v = rp[rg];
            v += __shfl_xor(v, 1, 64);
            v += __shfl_xor(v, 2, 64);
            v += __shfl_xor(v, 4, 64);
            v += __shfl_xor(v, 8, 64);
            if (r_ == 0) atomicAdd(&rowsum[wm * 128 + mi * 16 + q * 4 + rg], v);
        }
    }
    __syncthreads();
    if (tid < BM2) Zpart[(size_t)nb * MM + m0 + tid] = rowsum[tid];
}

// ---------------- Z[row] = sum over nblk of Zpart ----------------
__global__ __launch_bounds__(256) void zfinal_kernel(const float* __restrict__ Zpart,
                                                     float* __restrict__ Z) {
    int row = blockIdx.x * 256 + threadIdx.x;
    float s = 0.f;
    for (int nb = 0; nb < NBLK2; ++nb) s += Zpart[(size_t)nb * MM + row];
    Z[row] = s;
}

// ---------------- finalize: out = log(pg/Z * E + scatter((1-pg)*attn) + 1e-12) ----------------
template <bool E_BF16>
__global__ __launch_bounds__(256) void finalize_kernel(const void* __restrict__ E,
                                                       float* __restrict__ out,
                                                       const float* __restrict__ pg_arr,
                                                       const float* __restrict__ Z,
                                                       const float* __restrict__ attn,
                                                       const int* __restrict__ enc) {
    constexpr int CH = VV / 8;  // 4000
    __shared__ float acc[CH];
    int bid = blockIdx.x;
    int row = bid >> 3;
    int part = bid & 7;
    int nbase = part * CH;
    f32x4* acc4 = (f32x4*)acc;
    for (int j = threadIdx.x; j < CH / 4; j += 256) acc4[j] = (f32x4){0.f, 0.f, 0.f, 0.f};
    float pg = pg_arr[row];
    float scale = pg / Z[row];
    float om = 1.f - pg;
    int batch = row / TT;
    __syncthreads();
    for (int s = threadIdx.x; s < SS; s += 256) {
        int idx = enc[batch * SS + s];
        if (idx >= nbase && idx < nbase + CH)
            atomicAdd(&acc[idx - nbase], om * attn[(size_t)row * SS + s]);
    }
    __syncthreads();
    size_t base = (size_t)row * VV + nbase;
    for (int j = threadIdx.x * 8; j < CH; j += 2048) {
        float e[8];
        if (E_BF16) {
            ushort8 u = *(const ushort8*)((const unsigned short*)E + base + j);
            #pragma unroll
            for (int i = 0; i < 8; ++i) e[i] = bf2f(u[i]);
        } else {
            f32x4 u0 = *(const f32x4*)((const float*)E + base + j);
            f32x4 u1 = *(const f32x4*)((const float*)E + base + j + 4);
            e[0]=u0[0]; e[1]=u0[1]; e[2]=u0[2]; e[3]=u0[3];
            e[4]=u1[0]; e[5]=u1[1]; e[6]=u1[2]; e[7]=u1[3];
        }
        f32x4 a0 = acc4[(j >> 2) + 0];
        f32x4 a1 = acc4[(j >> 2) + 1];
        f32x4 o0, o1;
        #pragma unroll
        for (int i = 0; i < 4; ++i) o0[i] = __logf(scale * e[i]     + a0[i] + 1e-12f);
        #pragma unroll
        for (int i = 0; i < 4; ++i) o1[i] = __logf(scale * e[4 + i] + a1[i] + 1e-12f);
        *(f32x4*)(out + base + j)     = o0;
        *(f32x4*)(out + base + j + 4) = o1;
    }
}

extern "C" void kernel_launch(void* const* d_in, const int* in_sizes, int n_in,
                              void* d_out, int out_size, void* d_ws, size_t ws_size,
                              hipStream_t stream) {
    const float* s_output = (const float*)d_in[0];
    const float* state_in = (const float*)d_in[1];
    const float* attn     = (const float*)d_in[2];
    const int*   enc      = (const int*)  d_in[3];
    const float* w_pgen   = (const float*)d_in[4];
    const float* b_pgen   = (const float*)d_in[5];
    const float* w1       = (const float*)d_in[6];
    const float* b1       = (const float*)d_in[7];
    const float* w2       = (const float*)d_in[8];
    const float* b2       = (const float*)d_in[9];

    // workspace layout (bytes). Zpart aliases sA (sA dead after gemm1).
    char* ws = (char*)d_ws;
    float*          pg     = (float*)(ws + 0);                 // 2048 f32
    float*          Z      = (float*)(ws + 8192);              // 2048 f32
    unsigned short* hidden = (unsigned short*)(ws + 16384);    // 2048x512 bf16
    unsigned short* sA     = (unsigned short*)(ws + 2113536);  // 2048x512 bf16
    float*          Zpart  = (float*)(ws + 2113536);           // 125x2048 f32 (aliases sA)
    unsigned short* w1t    = (unsigned short*)(ws + 4210688);  // 512x512 bf16
    unsigned short* w2t    = (unsigned short*)(ws + 4734976);  // 32000x512 bf16 (end 37,502,976)
    unsigned short* Ebf    = (unsigned short*)(ws + 37502976); // 2048x32000 bf16 (needs big ws)

    const size_t NEED_BIG = 37502976ull + 2ull * MM * VV;      // 168,574,976
    const bool big = (ws_size >= NEED_BIG);

    f32_to_bf16_kernel<<<(MM * HH / 4 + 255) / 256, 256, 0, stream>>>(s_output, sA, MM * HH / 4);
    transpose_bf16_kernel<<<dim3(HH / 32, KK / 32), 256, 0, stream>>>(w1, w1t, KK, HH);
    transpose_bf16_kernel<<<dim3(VV / 32, KK / 32), 256, 0, stream>>>(w2, w2t, KK, VV);
    pgen_kernel<<<MM / 4, 256, 0, stream>>>(state_in, w_pgen, b_pgen, pg);
    gemm1_kernel<<<dim3(HH / 128, MM / 128), 256, 0, stream>>>(sA, w1t, b1, hidden, HH);

    if (big) {
        gemm2_exp_kernel<true><<<G2B, 512, 0, stream>>>(hidden, w2t, b2, Ebf, Zpart);
        zfinal_kernel<<<MM / 256, 256, 0, stream>>>(Zpart, Z);
        finalize_kernel<true><<<MM * 8, 256, 0, stream>>>(Ebf, (float*)d_out, pg, Z, attn, enc);
    } else {
        gemm2_exp_kernel<false><<<G2B, 512, 0, stream>>>(hidden, w2t, b2, d_out, Zpart);
        zfinal_kernel<<<MM / 256, 256, 0, stream>>>(Zpart, Z);
        finalize_kernel<false><<<MM * 8, 256, 0, stream>>>(d_out, (float*)d_out, pg, Z, attn, enc);
    }
}

// Round 3
// 510.876 us; speedup vs baseline: 1.0818x; 1.0013x over previous
//
#include <hip/hip_runtime.h>
#include <hip/hip_bf16.h>
#include <stdint.h>

// Problem constants: B=8, T=256, S=400, H=512, VOCAB=32000
#define BB 8
#define TT 256
#define SS 400
#define HH 512
#define VV 32000
#define MM (BB*TT)      // 2048 rows
#define KK 512

// gemm2 geometry: 256x256 tile, BK=32, 16 K-tiles, triple-buffered LDS
#define BM2 256
#define BN2 256
#define BK2 32
#define NT2 (KK/BK2)          // 16 K-tiles
#define NBLK2 (VV/BN2)        // 125 n-blocks
#define MBLK2 (MM/BM2)        // 8 m-blocks
#define G2B (NBLK2*MBLK2)     // 1000 blocks (divisible by 8 XCDs)

typedef __bf16 bf16x8 __attribute__((ext_vector_type(8)));
typedef float  f32x4  __attribute__((ext_vector_type(4)));
typedef unsigned short ushort8 __attribute__((ext_vector_type(8)));

__device__ __forceinline__ unsigned short f2bf(float x) {
    union { float f; unsigned u; } v; v.f = x;
    unsigned r = v.u + 0x7fffu + ((v.u >> 16) & 1u);   // RNE
    return (unsigned short)(r >> 16);
}
__device__ __forceinline__ float bf2f(unsigned short u) {
    union { unsigned u; float f; } v; v.u = ((unsigned)u) << 16; return v.f;
}

__device__ __forceinline__ void async_ld16(const void* g, void* lds) {
    __builtin_amdgcn_global_load_lds(
        (const __attribute__((address_space(1))) unsigned int*)g,
        (__attribute__((address_space(3))) unsigned int*)lds,
        16, 0, 0);
}

// ---------------- elementwise fp32 -> bf16 ----------------
__global__ __launch_bounds__(256) void f32_to_bf16_kernel(const float* __restrict__ x,
                                                          unsigned short* __restrict__ y, int n4) {
    int i = blockIdx.x * blockDim.x + threadIdx.x;
    if (i < n4) {
        float4 v = ((const float4*)x)[i];
        ushort4 o;
        o.x = f2bf(v.x); o.y = f2bf(v.y); o.z = f2bf(v.z); o.w = f2bf(v.w);
        ((ushort4*)y)[i] = o;
    }
}

// ---------------- transpose (K x N fp32) -> (N x K bf16) ----------------
__global__ __launch_bounds__(256) void transpose_bf16_kernel(const float* __restrict__ W,
                                                             unsigned short* __restrict__ Wt,
                                                             int K, int N) {
    __shared__ float tile[32][33];
    int n0 = blockIdx.x * 32, k0 = blockIdx.y * 32;
    int t = threadIdx.x;
    int r  = t >> 3;          // 0..31
    int c4 = (t & 7) * 4;     // 0,4,...,28
    float4 v = *(const float4*)(W + (size_t)(k0 + r) * N + n0 + c4);
    tile[r][c4 + 0] = v.x; tile[r][c4 + 1] = v.y;
    tile[r][c4 + 2] = v.z; tile[r][c4 + 3] = v.w;
    __syncthreads();
    ushort4 o;
    o.x = f2bf(tile[c4 + 0][r]);
    o.y = f2bf(tile[c4 + 1][r]);
    o.z = f2bf(tile[c4 + 2][r]);
    o.w = f2bf(tile[c4 + 3][r]);
    *(ushort4*)(Wt + (size_t)(n0 + r) * K + k0 + c4) = o;
}

// ---------------- p_gen ----------------
__global__ __launch_bounds__(256) void pgen_kernel(const float* __restrict__ state,
                                                   const float* __restrict__ wp,
                                                   const float* __restrict__ bp,
                                                   float* __restrict__ pg) {
    int row  = blockIdx.x * 4 + (threadIdx.x >> 6);
    int lane = threadIdx.x & 63;
    const float* s = state + (size_t)row * (2 * HH);
    float acc = 0.f;
    for (int j = lane; j < 2 * HH; j += 64) acc += s[j] * wp[j];
    for (int off = 32; off; off >>= 1) acc += __shfl_xor(acc, off, 64);
    if (lane == 0) pg[row] = 1.f / (1.f + __expf(-(acc + bp[0])));
}

// ---------------- GEMM1: hidden = bf16(A @ W1t^T + b1) ----------------
__global__ __launch_bounds__(256) void gemm1_kernel(const unsigned short* __restrict__ A,
                                                    const unsigned short* __restrict__ Bt,
                                                    const float* __restrict__ bias,
                                                    unsigned short* __restrict__ out, int N) {
    __shared__ __align__(16) unsigned short As[128 * 32];
    __shared__ __align__(16) unsigned short Bs[128 * 32];
    const int tid = threadIdx.x, wave = tid >> 6, lane = tid & 63;
    const int m0 = blockIdx.y * 128, n0 = blockIdx.x * 128;
    const int q = lane >> 4, r_ = lane & 15;
    const int wm = (wave >> 1) * 64, wn = (wave & 1) * 64;
    f32x4 acc[4][4] = {};
    for (int k0 = 0; k0 < KK; k0 += 32) {
        #pragma unroll
        for (int rr = 0; rr < 2; ++rr) {
            int cc = tid + rr * 256, row = cc >> 2, col = (cc & 3) * 8;
            async_ld16(A  + (size_t)(m0 + row) * KK + k0 + col, (char*)As + (size_t)cc * 16);
            async_ld16(Bt + (size_t)(n0 + row) * KK + k0 + col, (char*)Bs + (size_t)cc * 16);
        }
        __syncthreads();
        bf16x8 a[4], b[4];
        #pragma unroll
        for (int i = 0; i < 4; ++i) {
            a[i] = *(const bf16x8*)(As + (wm + i * 16 + r_) * 32 + q * 8);
            b[i] = *(const bf16x8*)(Bs + (wn + i * 16 + r_) * 32 + q * 8);
        }
        #pragma unroll
        for (int mi = 0; mi < 4; ++mi)
            #pragma unroll
            for (int ni = 0; ni < 4; ++ni)
                acc[mi][ni] = __builtin_amdgcn_mfma_f32_16x16x32_bf16(a[mi], b[ni], acc[mi][ni], 0, 0, 0);
        __syncthreads();
    }
    #pragma unroll
    for (int mi = 0; mi < 4; ++mi)
        #pragma unroll
        for (int ni = 0; ni < 4; ++ni) {
            int n = n0 + wn + ni * 16 + r_;
            float bv = bias[n];
            #pragma unroll
            for (int rg = 0; rg < 4; ++rg) {
                int m = m0 + wm + mi * 16 + q * 4 + rg;
                out[(size_t)m * N + n] = f2bf(acc[mi][ni][rg] + bv);
            }
        }
}

// ---------------- GEMM2 (256x256, BK=32, 8 waves, 3-buffer counted-vmcnt pipeline) ----
// E[m][n] = exp(hidden@w2t^T + b2); Zpart[nb][m] = sum over this block's 256 cols.
//
// Pipeline (T3+T4): 3 LDS buffers of one K-tile each (A 16KB | B 16KB). Tile t body:
//   vmcnt(4)            <- counted: waits stage(t)'s 4 loads; stage(t+1)'s 4 stay in flight
//   s_barrier           <- collective: ALL waves' stage(t) loads have landed
//   stage(t+2)          <- overwrites buf[(t-1)%3], whose reads all precede this barrier
//   12x ds_read_b128 -> 32 MFMA (setprio-wrapped)
// vmcnt never drains to 0 in the main loop (only final tile).
//
// LDS swizzle (both-sides, rule #21): 64B rows; slot ^= (row&3)^((row>>2)&3) gives
// 2-way bank aliasing (free) on ds_read_b128 vs 8-way for linear. global_load_lds
// dest is linear; the global SOURCE col is pre-inverse-swizzled; ds_read applies
// the same XOR.
template <bool E_BF16>
__global__ __launch_bounds__(512, 2) void gemm2_exp_kernel(const unsigned short* __restrict__ A,
                                                           const unsigned short* __restrict__ Bt,
                                                           const float* __restrict__ bias,
                                                           void* __restrict__ E,
                                                           float* __restrict__ Zpart) {
    __shared__ __align__(16) char lds[3][32768];   // [buf][ A:16384 | B:16384 ]
    const int tid = threadIdx.x, wave = tid >> 6, lane = tid & 63;
    const int q = lane >> 4, r_ = lane & 15;
    const int wm = wave >> 2;     // 0..1  -> M offset wm*128
    const int wn = wave & 3;      // 0..3  -> N offset wn*64

    // XCD-aware remap (bijective: 1000 % 8 == 0), m-inner within each XCD chunk
    const int bid = blockIdx.x;
    const int xcd = bid & 7;
    const int sub = bid >> 3;                  // 0..124
    const int lin = xcd * (G2B / 8) + sub;     // contiguous chunk per XCD
    const int nb  = lin >> 3;                  // 0..124
    const int mb  = lin & 7;                   // 0..7
    const int m0 = mb * BM2, n0 = nb * BN2;

    f32x4 acc[8][4] = {};   // [mi][ni]; wave patch = 128x64

    // stage K-tile t (A: 256x32, B: 256x32) into buf[t%3]; 4 loads/thread
    auto stage = [&](int t) {
        char* base = lds[t % 3];
        #pragma unroll
        for (int j = 0; j < 2; ++j) {
            int c    = tid + j * 512;              // 0..1023 (16B chunks)
            int row  = c >> 2;                     // 0..255
            int colb = (c & 3) * 16;               // linear LDS col-byte
            int swz  = (((row & 3) ^ ((row >> 2) & 3)) << 4);
            int src  = colb ^ swz;                 // inverse-swizzled source col-byte
            async_ld16((const char*)A  + ((size_t)(m0 + row) * KK + t * BK2) * 2 + src,
                       base + c * 16);
            async_ld16((const char*)Bt + ((size_t)(n0 + row) * KK + t * BK2) * 2 + src,
                       base + 16384 + c * 16);
        }
    };

    // prologue: stage tiles 0 and 1 (8 loads in flight)
    stage(0);
    stage(1);

    for (int t = 0; t < NT2; ++t) {
        if (t < NT2 - 1) asm volatile("s_waitcnt vmcnt(4)" ::: "memory");
        else             asm volatile("s_waitcnt vmcnt(0)" ::: "memory");
        __builtin_amdgcn_sched_barrier(0);
        __builtin_amdgcn_s_barrier();
        __builtin_amdgcn_sched_barrier(0);
        if (t + 2 < NT2) stage(t + 2);

        char* buf = lds[t % 3];
        bf16x8 af[8], bg[4];
        #pragma unroll
        for (int mi = 0; mi < 8; ++mi) {
            int row = wm * 128 + mi * 16 + r_;
            int cb  = (q * 16) ^ (((row & 3) ^ ((row >> 2) & 3)) << 4);
            af[mi] = *(const bf16x8*)(buf + row * 64 + cb);
        }
        #pragma unroll
        for (int ni = 0; ni < 4; ++ni) {
            int row = wn * 64 + ni * 16 + r_;
            int cb  = (q * 16) ^ (((row & 3) ^ ((row >> 2) & 3)) << 4);
            bg[ni] = *(const bf16x8*)(buf + 16384 + row * 64 + cb);
        }
        __builtin_amdgcn_s_setprio(1);
        #pragma unroll
        for (int mi = 0; mi < 8; ++mi)
            #pragma unroll
            for (int ni = 0; ni < 4; ++ni)
                acc[mi][ni] = __builtin_amdgcn_mfma_f32_16x16x32_bf16(
                    af[mi], bg[ni], acc[mi][ni], 0, 0, 0);
        __builtin_amdgcn_s_setprio(0);
        __builtin_amdgcn_sched_barrier(0);
    }

    // ---- epilogue: exp, E store, per-row sums (rowsum overlays dead staging LDS) ----
    __syncthreads();   // all reads of buffers done before overlay
    float* rowsum = (float*)&lds[0][0];
    if (tid < BM2) rowsum[tid] = 0.f;
    __syncthreads();

    float bv[4];
    #pragma unroll
    for (int ni = 0; ni < 4; ++ni) bv[ni] = bias[n0 + wn * 64 + ni * 16 + r_];

    #pragma unroll
    for (int mi = 0; mi < 8; ++mi) {
        float rp[4] = {0.f, 0.f, 0.f, 0.f};
        #pragma unroll
        for (int ni = 0; ni < 4; ++ni) {
            int n = n0 + wn * 64 + ni * 16 + r_;
            #pragma unroll
            for (int rg = 0; rg < 4; ++rg) {
                int m = m0 + wm * 128 + mi * 16 + q * 4 + rg;
                float e = __expf(acc[mi][ni][rg] + bv[ni]);
                if (E_BF16)
                    ((unsigned short*)E)[(size_t)m * VV + n] = f2bf(e);
                else
                    ((float*)E)[(size_t)m * VV + n] = e;
                rp[rg] += e;
            }
        }
        #pragma unroll
        for (int rg = 0; rg < 4; ++rg) {
            float v = rp[rg];
            v += __shfl_xor(v, 1, 64);
            v += __shfl_xor(v, 2, 64);
            v += __shfl_xor(v, 4, 64);
            v += __shfl_xor(v, 8, 64);
            if (r_ == 0) atomicAdd(&rowsum[wm * 128 + mi * 16 + q * 4 + rg], v);
        }
    }
    __syncthreads();
    if (tid < BM2) Zpart[(size_t)nb * MM + m0 + tid] = rowsum[tid];
}

// ---------------- Z[row] = sum over nblk of Zpart ----------------
__global__ __launch_bounds__(256) void zfinal_kernel(const float* __restrict__ Zpart,
                                                     float* __restrict__ Z) {
    int row = blockIdx.x * 256 + threadIdx.x;
    float s = 0.f;
    for (int nb = 0; nb < NBLK2; ++nb) s += Zpart[(size_t)nb * MM + row];
    Z[row] = s;
}

// ---------------- finalize: out = log(pg/Z * E + scatter((1-pg)*attn) + 1e-12) ----------------
template <bool E_BF16>
__global__ __launch_bounds__(256) void finalize_kernel(const void* __restrict__ E,
                                                       float* __restrict__ out,
                                                       const float* __restrict__ pg_arr,
                                                       const float* __restrict__ Z,
                                                       const float* __restrict__ attn,
                                                       const int* __restrict__ enc) {
    constexpr int CH = VV / 8;  // 4000
    __shared__ float acc[CH];
    int bid = blockIdx.x;
    int row = bid >> 3;
    int part = bid & 7;
    int nbase = part * CH;
    f32x4* acc4 = (f32x4*)acc;
    for (int j = threadIdx.x; j < CH / 4; j += 256) acc4[j] = (f32x4){0.f, 0.f, 0.f, 0.f};
    float pg = pg_arr[row];
    float scale = pg / Z[row];
    float om = 1.f - pg;
    int batch = row / TT;
    __syncthreads();
    for (int s = threadIdx.x; s < SS; s += 256) {
        int idx = enc[batch * SS + s];
        if (idx >= nbase && idx < nbase + CH)
            atomicAdd(&acc[idx - nbase], om * attn[(size_t)row * SS + s]);
    }
    __syncthreads();
    size_t base = (size_t)row * VV + nbase;
    for (int j = threadIdx.x * 8; j < CH; j += 2048) {
        float e[8];
        if (E_BF16) {
            ushort8 u = *(const ushort8*)((const unsigned short*)E + base + j);
            #pragma unroll
            for (int i = 0; i < 8; ++i) e[i] = bf2f(u[i]);
        } else {
            f32x4 u0 = *(const f32x4*)((const float*)E + base + j);
            f32x4 u1 = *(const f32x4*)((const float*)E + base + j + 4);
            e[0]=u0[0]; e[1]=u0[1]; e[2]=u0[2]; e[3]=u0[3];
            e[4]=u1[0]; e[5]=u1[1]; e[6]=u1[2]; e[7]=u1[3];
        }
        f32x4 a0 = acc4[(j >> 2) + 0];
        f32x4 a1 = acc4[(j >> 2) + 1];
        f32x4 o0, o1;
        #pragma unroll
        for (int i = 0; i < 4; ++i) o0[i] = __logf(scale * e[i]     + a0[i] + 1e-12f);
        #pragma unroll
        for (int i = 0; i < 4; ++i) o1[i] = __logf(scale * e[4 + i] + a1[i] + 1e-12f);
        *(f32x4*)(out + base + j)     = o0;
        *(f32x4*)(out + base + j + 4) = o1;
    }
}

extern "C" void kernel_launch(void* const* d_in, const int* in_sizes, int n_in,
                              void* d_out, int out_size, void* d_ws, size_t ws_size,
                              hipStream_t stream) {
    const float* s_output = (const float*)d_in[0];
    const float* state_in = (const float*)d_in[1];
    const float* attn     = (const float*)d_in[2];
    const int*   enc      = (const int*)  d_in[3];
    const float* w_pgen   = (const float*)d_in[4];
    const float* b_pgen   = (const float*)d_in[5];
    const float* w1       = (const float*)d_in[6];
    const float* b1       = (const float*)d_in[7];
    const float* w2       = (const float*)d_in[8];
    const float* b2       = (const float*)d_in[9];

    // workspace layout (bytes). Zpart aliases sA (sA dead after gemm1).
    char* ws = (char*)d_ws;
    float*          pg     = (float*)(ws + 0);                 // 2048 f32
    float*          Z      = (float*)(ws + 8192);              // 2048 f32
    unsigned short* hidden = (unsigned short*)(ws + 16384);    // 2048x512 bf16
    unsigned short* sA     = (unsigned short*)(ws + 2113536);  // 2048x512 bf16
    float*          Zpart  = (float*)(ws + 2113536);           // 125x2048 f32 (aliases sA)
    unsigned short* w1t    = (unsigned short*)(ws + 4210688);  // 512x512 bf16
    unsigned short* w2t    = (unsigned short*)(ws + 4734976);  // 32000x512 bf16 (end 37,502,976)
    unsigned short* Ebf    = (unsigned short*)(ws + 37502976); // 2048x32000 bf16 (needs big ws)

    const size_t NEED_BIG = 37502976ull + 2ull * MM * VV;      // 168,574,976
    const bool big = (ws_size >= NEED_BIG);

    f32_to_bf16_kernel<<<(MM * HH / 4 + 255) / 256, 256, 0, stream>>>(s_output, sA, MM * HH / 4);
    transpose_bf16_kernel<<<dim3(HH / 32, KK / 32), 256, 0, stream>>>(w1, w1t, KK, HH);
    transpose_bf16_kernel<<<dim3(VV / 32, KK / 32), 256, 0, stream>>>(w2, w2t, KK, VV);
    pgen_kernel<<<MM / 4, 256, 0, stream>>>(state_in, w_pgen, b_pgen, pg);
    gemm1_kernel<<<dim3(HH / 128, MM / 128), 256, 0, stream>>>(sA, w1t, b1, hidden, HH);

    if (big) {
        gemm2_exp_kernel<true><<<G2B, 512, 0, stream>>>(hidden, w2t, b2, Ebf, Zpart);
        zfinal_kernel<<<MM / 256, 256, 0, stream>>>(Zpart, Z);
        finalize_kernel<true><<<MM * 8, 256, 0, stream>>>(Ebf, (float*)d_out, pg, Z, attn, enc);
    } else {
        gemm2_exp_kernel<false><<<G2B, 512, 0, stream>>>(hidden, w2t, b2, d_out, Zpart);
        zfinal_kernel<<<MM / 256, 256, 0, stream>>>(Zpart, Z);
        finalize_kernel<false><<<MM * 8, 256, 0, stream>>>(d_out, (float*)d_out, pg, Z, attn, enc);
    }
}